// Round 1
// baseline (13978.925 us; speedup 1.0000x reference)
//
#include <hip/hip_runtime.h>
#include <math.h>

// Problem constants (fixed by the reference)
#define BATCH   2
#define NQ_CB   4
#define T_SEQ   1024
#define DMODEL  1024
#define NHEAD   16
#define HDIM    64
#define NLAYER  8
#define CARD_SZ 1024
#define NCOND   64
#define CONDD   768
#define DFF_SZ  4096
#define WIN     5

// ---------------------------------------------------------------------------
// Embedding sum over 4 codebooks + interleaved sin/cos positional embedding
// h[b,t,:] = sum_q emb[q][x[b,q,t]] + pos(t)
// grid = B*T blocks, 256 threads, float4 per thread (D=1024)
// ---------------------------------------------------------------------------
__global__ __launch_bounds__(256) void embed_kernel(
    const int* __restrict__ x, const float* __restrict__ emb,
    float* __restrict__ h)
{
  int bt = blockIdx.x;             // b*T + t
  int b = bt >> 10, t = bt & (T_SEQ - 1);
  int tid = threadIdx.x;           // float4 index into the row
  float4 acc = make_float4(0.f, 0.f, 0.f, 0.f);
#pragma unroll
  for (int q = 0; q < NQ_CB; ++q) {
    int idx = x[(b * NQ_CB + q) * T_SEQ + t];
    const float4* er =
        (const float4*)(emb + ((size_t)q * (CARD_SZ + 1) + idx) * DMODEL);
    float4 e = er[tid];
    acc.x += e.x; acc.y += e.y; acc.z += e.z; acc.w += e.w;
  }
  // positional: element d: j = d>>1, theta = t * 10000^(-2j/D); even->sin, odd->cos
  int d0 = tid * 4;
  float c = -logf(10000.f) * (2.f / (float)DMODEL);
  float th0 = (float)t * expf(c * (float)(d0 >> 1));
  float th1 = (float)t * expf(c * (float)((d0 + 2) >> 1));
  acc.x += sinf(th0); acc.y += cosf(th0);
  acc.z += sinf(th1); acc.w += cosf(th1);
  ((float4*)(h + (size_t)bt * DMODEL))[tid] = acc;
}

// ---------------------------------------------------------------------------
// LayerNorm over last dim (D=1024). One block (256 thr) per row.
// ---------------------------------------------------------------------------
__global__ __launch_bounds__(256) void ln_kernel(
    const float* __restrict__ x, const float* __restrict__ g,
    const float* __restrict__ b, float* __restrict__ y)
{
  int row = blockIdx.x;
  int tid = threadIdx.x;
  const float4* xr = (const float4*)(x + (size_t)row * DMODEL);
  float4 v = xr[tid];
  float s  = v.x + v.y + v.z + v.w;
  float ss = v.x * v.x + v.y * v.y + v.z * v.z + v.w * v.w;
#pragma unroll
  for (int off = 32; off; off >>= 1) {
    s  += __shfl_xor(s, off, 64);
    ss += __shfl_xor(ss, off, 64);
  }
  __shared__ float sh_s[4], sh_ss[4];
  int w = tid >> 6;
  if ((tid & 63) == 0) { sh_s[w] = s; sh_ss[w] = ss; }
  __syncthreads();
  s  = sh_s[0] + sh_s[1] + sh_s[2] + sh_s[3];
  ss = sh_ss[0] + sh_ss[1] + sh_ss[2] + sh_ss[3];
  float mean = s * (1.f / DMODEL);
  float var  = ss * (1.f / DMODEL) - mean * mean;
  float rstd = rsqrtf(var + 1e-5f);
  float4 gv = ((const float4*)g)[tid];
  float4 bv = ((const float4*)b)[tid];
  float4 o;
  o.x = (v.x - mean) * rstd * gv.x + bv.x;
  o.y = (v.y - mean) * rstd * gv.y + bv.y;
  o.z = (v.z - mean) * rstd * gv.z + bv.z;
  o.w = (v.w - mean) * rstd * gv.w + bv.w;
  ((float4*)(y + (size_t)row * DMODEL))[tid] = o;
}

// ---------------------------------------------------------------------------
// fp32 SGEMM: C[m,n] = A[m,:] @ W[:,n] (+bias) (+gelu) (+resid)
// A: (M,K) row-major, W: (K,N) row-major.
// Block tile 128x64, BK=16, 256 threads, 8x4 micro-tile per thread.
// head_q >= 0: output row m=(b,t) remapped to out[b, head_q, t, :] (CARD cols).
// ---------------------------------------------------------------------------
__global__ __launch_bounds__(256) void gemm_kernel(
    const float* __restrict__ A, const float* __restrict__ W,
    const float* __restrict__ bias, const float* __restrict__ resid,
    float* __restrict__ C, int M, int N, int K, int do_gelu, int head_q)
{
  const int BM = 128, BN = 64, BK = 16;
  // +4 pad keeps k-row bases 16B-aligned for ds_read_b128 and <=2-way conflicts
  __shared__ float As[BK][BM + 4];
  __shared__ float Bs[BK][BN];

  int tid = threadIdx.x;
  int tx = tid & 15;    // n-dim: 16 * 4 = 64
  int ty = tid >> 4;    // m-dim: 16 * 8 = 128
  int block_m = blockIdx.y * BM;
  int block_n = blockIdx.x * BN;

  float acc[8][4];
#pragma unroll
  for (int i = 0; i < 8; ++i)
#pragma unroll
    for (int j = 0; j < 4; ++j) acc[i][j] = 0.f;

  for (int k0 = 0; k0 < K; k0 += BK) {
    // A tile: 128 rows x 16 k = 512 float4; 2 per thread
#pragma unroll
    for (int i = 0; i < 2; ++i) {
      int idx = tid + i * 256;          // 0..511
      int m   = idx >> 2;               // 0..127
      int kv  = (idx & 3) << 2;         // 0,4,8,12
      float4 av = *(const float4*)(A + (size_t)(block_m + m) * K + k0 + kv);
      As[kv + 0][m] = av.x;
      As[kv + 1][m] = av.y;
      As[kv + 2][m] = av.z;
      As[kv + 3][m] = av.w;
    }
    // B tile: 16 k x 64 n = 256 float4; 1 per thread
    {
      int k  = tid >> 4;
      int n4 = (tid & 15) << 2;
      float4 bv4 = *(const float4*)(W + (size_t)(k0 + k) * N + block_n + n4);
      *(float4*)(&Bs[k][n4]) = bv4;
    }
    __syncthreads();
#pragma unroll
    for (int k = 0; k < BK; ++k) {
      float4 a0 = *(const float4*)&As[k][ty * 8];
      float4 a1 = *(const float4*)&As[k][ty * 8 + 4];
      float4 b0 = *(const float4*)&Bs[k][tx * 4];
      float av[8] = {a0.x, a0.y, a0.z, a0.w, a1.x, a1.y, a1.z, a1.w};
      float bv[4] = {b0.x, b0.y, b0.z, b0.w};
#pragma unroll
      for (int i = 0; i < 8; ++i)
#pragma unroll
        for (int j = 0; j < 4; ++j) acc[i][j] += av[i] * bv[j];
    }
    __syncthreads();
  }

  // epilogue
#pragma unroll
  for (int i = 0; i < 8; ++i) {
    int m = block_m + ty * 8 + i;
    float* crow;
    if (head_q >= 0) {
      int bb = m >> 10, tt = m & (T_SEQ - 1);
      crow = C + ((size_t)((bb * NQ_CB + head_q) * T_SEQ + tt)) * CARD_SZ;
    } else {
      crow = C + (size_t)m * N;
    }
    int n = block_n + tx * 4;
    float v[4];
#pragma unroll
    for (int j = 0; j < 4; ++j) v[j] = acc[i][j];
    if (bias) {
      float4 b4 = *(const float4*)(bias + n);
      v[0] += b4.x; v[1] += b4.y; v[2] += b4.z; v[3] += b4.w;
    }
    if (do_gelu) {
#pragma unroll
      for (int j = 0; j < 4; ++j) {
        float xx = v[j];
        v[j] = 0.5f * xx *
               (1.f + tanhf(0.7978845608028654f * (xx + 0.044715f * xx * xx * xx)));
      }
    }
    if (resid) {
      float4 r4 = *(const float4*)(resid + (size_t)m * N + n);
      v[0] += r4.x; v[1] += r4.y; v[2] += r4.z; v[3] += r4.w;
    }
    *(float4*)(crow + n) = make_float4(v[0], v[1], v[2], v[3]);
  }
}

// ---------------------------------------------------------------------------
// Banded self-attention, WIN=5: 11 keys per query. One wave per (b,h,t);
// lane = head-dim element. Scores via wave shuffle-reduce.
// q,k,v,o: (B,T,D) with heads as D = H*64 slices.
// ---------------------------------------------------------------------------
__global__ __launch_bounds__(256) void self_attn_kernel(
    const float* __restrict__ q, const float* __restrict__ k,
    const float* __restrict__ v, float* __restrict__ o)
{
  int w = blockIdx.x * 4 + (threadIdx.x >> 6);  // (b*NHEAD + h)*T + t
  int lane = threadIdx.x & 63;
  int t = w & (T_SEQ - 1);
  int bh = w >> 10;
  int h = bh & (NHEAD - 1);
  int b = bh >> 4;
  size_t base = ((size_t)(b * T_SEQ) * DMODEL) + h * HDIM + lane;
  float qv = q[base + (size_t)t * DMODEL];

  float sc[2 * WIN + 1];
  float mx = -1e30f;
#pragma unroll
  for (int j = 0; j < 2 * WIN + 1; ++j) {
    int s = t - WIN + j;
    float d;
    if (s >= 0 && s < T_SEQ) {
      float kv = k[base + (size_t)s * DMODEL];
      d = qv * kv;
#pragma unroll
      for (int off = 32; off; off >>= 1) d += __shfl_xor(d, off, 64);
      d *= 0.125f;  // 1/sqrt(64)
    } else {
      d = -1e30f;
    }
    sc[j] = d;
    mx = fmaxf(mx, d);
  }
  float sum = 0.f;
#pragma unroll
  for (int j = 0; j < 2 * WIN + 1; ++j) {
    sc[j] = expf(sc[j] - mx);  // out-of-band: exp(-1e30-mx) == 0
    sum += sc[j];
  }
  float inv = 1.f / sum;
  float ov = 0.f;
#pragma unroll
  for (int j = 0; j < 2 * WIN + 1; ++j) {
    int s = t - WIN + j;
    if (s >= 0 && s < T_SEQ) ov += sc[j] * v[base + (size_t)s * DMODEL];
  }
  o[base + (size_t)t * DMODEL] = ov * inv;
}

// ---------------------------------------------------------------------------
// Cross-attention over NCOND=64 keys. One wave per (b,h,t).
// Phase 1: lane = key index s (64 == NCOND). Phase 2: lane = head-dim d.
// ---------------------------------------------------------------------------
__global__ __launch_bounds__(256) void cross_attn_kernel(
    const float* __restrict__ q, const float* __restrict__ k,
    const float* __restrict__ v, float* __restrict__ o)
{
  int w = blockIdx.x * 4 + (threadIdx.x >> 6);  // (b*NHEAD + h)*T + t
  int lane = threadIdx.x & 63;
  int t = w & (T_SEQ - 1);
  int h = (w >> 10) & (NHEAD - 1);
  int b = w >> 14;
  size_t qoff = ((size_t)(b * T_SEQ + t) * DMODEL) + h * HDIM;
  float qv = q[qoff + lane];

  // scores: lane s computes q . k[s]
  const float* krow = k + ((size_t)(b * NCOND + lane) * DMODEL) + h * HDIM;
  float s_l = 0.f;
#pragma unroll
  for (int d = 0; d < HDIM; ++d) {
    float qd = __shfl(qv, d, 64);
    s_l += qd * krow[d];
  }
  s_l *= 0.125f;
  float m = s_l;
#pragma unroll
  for (int off = 32; off; off >>= 1) m = fmaxf(m, __shfl_xor(m, off, 64));
  float p = expf(s_l - m);
  float sum = p;
#pragma unroll
  for (int off = 32; off; off >>= 1) sum += __shfl_xor(sum, off, 64);
  p /= sum;

  // output: lane d accumulates sum_s p_s * v[s][d]
  float ov = 0.f;
  const float* vb = v + ((size_t)(b * NCOND) * DMODEL) + h * HDIM + lane;
#pragma unroll
  for (int s = 0; s < NCOND; ++s) {
    float ps = __shfl(p, s, 64);
    ov += ps * vb[(size_t)s * DMODEL];
  }
  o[qoff + lane] = ov;
}

// ---------------------------------------------------------------------------
// Host-side launch
// ---------------------------------------------------------------------------
static inline void gemm(hipStream_t st, const float* A, const float* W,
                        const float* bias, const float* resid, float* C,
                        int M, int N, int K, int do_gelu, int head_q)
{
  dim3 grid(N / 64, M / 128);
  hipLaunchKernelGGL(gemm_kernel, grid, dim3(256), 0, st, A, W, bias, resid, C,
                     M, N, K, do_gelu, head_q);
}

static inline void layernorm(hipStream_t st, const float* x, const float* g,
                             const float* b, float* y, int rows)
{
  hipLaunchKernelGGL(ln_kernel, dim3(rows), dim3(256), 0, st, x, g, b, y);
}

extern "C" void kernel_launch(void* const* d_in, const int* in_sizes, int n_in,
                              void* d_out, int out_size, void* d_ws, size_t ws_size,
                              hipStream_t stream)
{
  const int*   x     = (const int*)  d_in[0];
  const float* cond  = (const float*)d_in[1];
  const float* emb   = (const float*)d_in[2];
  const float* ln1_g = (const float*)d_in[3];
  const float* ln1_b = (const float*)d_in[4];
  const float* ln2_g = (const float*)d_in[5];
  const float* ln2_b = (const float*)d_in[6];
  const float* ln3_g = (const float*)d_in[7];
  const float* ln3_b = (const float*)d_in[8];
  const float* sWq   = (const float*)d_in[9];
  const float* sWk   = (const float*)d_in[10];
  const float* sWv   = (const float*)d_in[11];
  const float* sWo   = (const float*)d_in[12];
  const float* sbq   = (const float*)d_in[13];
  const float* sbk   = (const float*)d_in[14];
  const float* sbv   = (const float*)d_in[15];
  const float* sbo   = (const float*)d_in[16];
  const float* cWq   = (const float*)d_in[17];
  const float* cWk   = (const float*)d_in[18];
  const float* cWv   = (const float*)d_in[19];
  const float* cWo   = (const float*)d_in[20];
  const float* cbq   = (const float*)d_in[21];
  const float* cbk   = (const float*)d_in[22];
  const float* cbv   = (const float*)d_in[23];
  const float* cbo   = (const float*)d_in[24];
  const float* W1    = (const float*)d_in[25];
  const float* b1    = (const float*)d_in[26];
  const float* W2    = (const float*)d_in[27];
  const float* b2    = (const float*)d_in[28];
  const float* out_g = (const float*)d_in[29];
  const float* out_b = (const float*)d_in[30];
  const float* headW = (const float*)d_in[31];
  const float* headb = (const float*)d_in[32];

  float* out = (float*)d_out;
  float* ws  = (float*)d_ws;

  const int M = BATCH * T_SEQ;             // 2048
  const size_t SZ = (size_t)M * DMODEL;    // 2M floats (8 MB)
  float* h   = ws;
  float* tmp = ws + SZ;
  float* qb  = ws + 2 * SZ;
  float* kb  = ws + 3 * SZ;
  float* vb  = ws + 4 * SZ;
  float* ao  = ws + 5 * SZ;
  float* ffn = qb;  // (M, DFF) = 4*SZ floats, aliases qb..ao (free during FFN)
  // total ws use: 6*SZ floats = 50.3 MB

  hipLaunchKernelGGL(embed_kernel, dim3(M), dim3(256), 0, stream, x, emb, h);

  const int attn_blocks = BATCH * NHEAD * T_SEQ / 4;  // 4 waves per block

  for (int l = 0; l < NLAYER; ++l) {
    const size_t wDD = (size_t)l * DMODEL * DMODEL;
    const size_t wCD = (size_t)l * CONDD * DMODEL;
    const size_t wF1 = (size_t)l * DMODEL * DFF_SZ;
    const size_t wF2 = (size_t)l * DFF_SZ * DMODEL;

    // --- self attention block ---
    layernorm(stream, h, ln1_g + l * DMODEL, ln1_b + l * DMODEL, tmp, M);
    gemm(stream, tmp, sWq + wDD, sbq + l * DMODEL, nullptr, qb, M, DMODEL, DMODEL, 0, -1);
    gemm(stream, tmp, sWk + wDD, sbk + l * DMODEL, nullptr, kb, M, DMODEL, DMODEL, 0, -1);
    gemm(stream, tmp, sWv + wDD, sbv + l * DMODEL, nullptr, vb, M, DMODEL, DMODEL, 0, -1);
    hipLaunchKernelGGL(self_attn_kernel, dim3(attn_blocks), dim3(256), 0, stream,
                       qb, kb, vb, ao);
    gemm(stream, ao, sWo + wDD, sbo + l * DMODEL, h, h, M, DMODEL, DMODEL, 0, -1);

    // --- cross attention block ---
    layernorm(stream, h, ln2_g + l * DMODEL, ln2_b + l * DMODEL, tmp, M);
    gemm(stream, tmp, cWq + wDD, cbq + l * DMODEL, nullptr, qb, M, DMODEL, DMODEL, 0, -1);
    gemm(stream, cond, cWk + wCD, cbk + l * DMODEL, nullptr, kb,
         BATCH * NCOND, DMODEL, CONDD, 0, -1);
    gemm(stream, cond, cWv + wCD, cbv + l * DMODEL, nullptr, vb,
         BATCH * NCOND, DMODEL, CONDD, 0, -1);
    hipLaunchKernelGGL(cross_attn_kernel, dim3(attn_blocks), dim3(256), 0, stream,
                       qb, kb, vb, ao);
    gemm(stream, ao, cWo + wDD, cbo + l * DMODEL, h, h, M, DMODEL, DMODEL, 0, -1);

    // --- FFN block ---
    layernorm(stream, h, ln3_g + l * DMODEL, ln3_b + l * DMODEL, tmp, M);
    gemm(stream, tmp, W1 + wF1, b1 + l * DFF_SZ, nullptr, ffn, M, DFF_SZ, DMODEL, 1, -1);
    gemm(stream, ffn, W2 + wF2, b2 + l * DMODEL, h, h, M, DMODEL, DFF_SZ, 0, -1);
  }

  // --- output norm + per-codebook heads ---
  layernorm(stream, h, out_g, out_b, tmp, M);
  for (int qi = 0; qi < NQ_CB; ++qi) {
    gemm(stream, tmp, headW + (size_t)qi * DMODEL * CARD_SZ, headb + qi * CARD_SZ,
         nullptr, out, M, CARD_SZ, DMODEL, 0, qi);
  }
}

// Round 2
// 4929.830 us; speedup vs baseline: 2.8356x; 2.8356x over previous
//
#include <hip/hip_runtime.h>
#include <math.h>

// Problem constants (fixed by the reference)
#define BATCH   2
#define NQ_CB   4
#define T_SEQ   1024
#define DMODEL  1024
#define NHEAD   16
#define HDIM    64
#define NLAYER  8
#define CARD_SZ 1024
#define NCOND   64
#define CONDD   768
#define DFF_SZ  4096
#define WIN     5

typedef __attribute__((ext_vector_type(8))) short bf16x8;
typedef __attribute__((ext_vector_type(4))) float f32x4;

// float -> bf16 (RNE) as raw short
__device__ inline short f2bf(float f) {
  union { float f; unsigned u; } c;
  c.f = f;
  unsigned r = (c.u + 0x7FFFu + ((c.u >> 16) & 1u)) >> 16;
  return (short)r;
}

// ---------------------------------------------------------------------------
// Embedding sum over 4 codebooks + interleaved sin/cos positional embedding
// ---------------------------------------------------------------------------
__global__ __launch_bounds__(256) void embed_kernel(
    const int* __restrict__ x, const float* __restrict__ emb,
    float* __restrict__ h)
{
  int bt = blockIdx.x;             // b*T + t
  int b = bt >> 10, t = bt & (T_SEQ - 1);
  int tid = threadIdx.x;           // float4 index into the row
  float4 acc = make_float4(0.f, 0.f, 0.f, 0.f);
#pragma unroll
  for (int q = 0; q < NQ_CB; ++q) {
    int idx = x[(b * NQ_CB + q) * T_SEQ + t];
    const float4* er =
        (const float4*)(emb + ((size_t)q * (CARD_SZ + 1) + idx) * DMODEL);
    float4 e = er[tid];
    acc.x += e.x; acc.y += e.y; acc.z += e.z; acc.w += e.w;
  }
  int d0 = tid * 4;
  float c = -logf(10000.f) * (2.f / (float)DMODEL);
  float th0 = (float)t * expf(c * (float)(d0 >> 1));
  float th1 = (float)t * expf(c * (float)((d0 + 2) >> 1));
  acc.x += sinf(th0); acc.y += cosf(th0);
  acc.z += sinf(th1); acc.w += cosf(th1);
  ((float4*)(h + (size_t)bt * DMODEL))[tid] = acc;
}

// ---------------------------------------------------------------------------
// LayerNorm over last dim (D=1024). One block (256 thr) per row.
// ---------------------------------------------------------------------------
__global__ __launch_bounds__(256) void ln_kernel(
    const float* __restrict__ x, const float* __restrict__ g,
    const float* __restrict__ b, float* __restrict__ y)
{
  int row = blockIdx.x;
  int tid = threadIdx.x;
  const float4* xr = (const float4*)(x + (size_t)row * DMODEL);
  float4 v = xr[tid];
  float s  = v.x + v.y + v.z + v.w;
  float ss = v.x * v.x + v.y * v.y + v.z * v.z + v.w * v.w;
#pragma unroll
  for (int off = 32; off; off >>= 1) {
    s  += __shfl_xor(s, off, 64);
    ss += __shfl_xor(ss, off, 64);
  }
  __shared__ float sh_s[4], sh_ss[4];
  int w = tid >> 6;
  if ((tid & 63) == 0) { sh_s[w] = s; sh_ss[w] = ss; }
  __syncthreads();
  s  = sh_s[0] + sh_s[1] + sh_s[2] + sh_s[3];
  ss = sh_ss[0] + sh_ss[1] + sh_ss[2] + sh_ss[3];
  float mean = s * (1.f / DMODEL);
  float var  = ss * (1.f / DMODEL) - mean * mean;
  float rstd = rsqrtf(var + 1e-5f);
  float4 gv = ((const float4*)g)[tid];
  float4 bv = ((const float4*)b)[tid];
  float4 o;
  o.x = (v.x - mean) * rstd * gv.x + bv.x;
  o.y = (v.y - mean) * rstd * gv.y + bv.y;
  o.z = (v.z - mean) * rstd * gv.z + bv.z;
  o.w = (v.w - mean) * rstd * gv.w + bv.w;
  ((float4*)(y + (size_t)row * DMODEL))[tid] = o;
}

// ---------------------------------------------------------------------------
// bf16 MFMA GEMM with in-register fp32->bf16 conversion during staging.
// C[m,n] = A[m,:] @ W[:,n] (+bias) (+gelu) (+resid, fp32)
// A: (M,K) fp32 row-major, W: (K,N) fp32 row-major; C fp32.
// Tile: BM x 128, BK=32. 256 threads = 4 waves in 2x2.
// MW = m16-groups per wave (4 -> BM=128, 2 -> BM=64).
// grid.z batching: wstride!=0 -> W = W0 + z*wstride (heads); else pointer
// select among W0/W1/W2 (QKV, cross-KV).
// head_remap: output row m=(b*T+t) -> [b, z, t, :] of (B,NQ,T,CARD).
// LDS layout: fragment-contiguous 1KB groups; a wave's ds_read_b128 covers
// a full contiguous 1KB (m134 conflict-free case).
// ---------------------------------------------------------------------------
template <int MW>
__global__ __launch_bounds__(256) void gemm_bf16_kernel(
    const float* __restrict__ A,
    const float* __restrict__ W0, const float* __restrict__ W1,
    const float* __restrict__ W2, size_t wstride,
    const float* __restrict__ bias0, const float* __restrict__ bias1,
    const float* __restrict__ bias2, size_t bstride,
    const float* __restrict__ resid,
    float* __restrict__ C0, float* __restrict__ C1, float* __restrict__ C2,
    int M, int N, int K, int do_gelu, int head_remap)
{
  const int BK = 32;
  const int BM = MW * 32;          // 2 waves stacked in m
  const int BN = 128;

  __shared__ __align__(16) short Als[BM * BK];   // (BM/16) groups of 512 shorts
  __shared__ __align__(16) short Bls[BN * BK];   // 8 groups of 512 shorts

  int tid = threadIdx.x;
  int z = blockIdx.z;
  const float* W    = wstride ? W0 + (size_t)z * wstride
                              : (z == 0 ? W0 : (z == 1 ? W1 : W2));
  const float* bias = wstride ? bias0 + (size_t)z * bstride
                              : (z == 0 ? bias0 : (z == 1 ? bias1 : bias2));
  float* C = (wstride || z == 0) ? C0 : (z == 1 ? C1 : C2);

  int bm = blockIdx.y * BM;
  int bn = blockIdx.x * BN;
  int wave = tid >> 6, lane = tid & 63;
  int wm = (wave >> 1) * (MW * 16);   // wave m-offset within tile
  int wn = (wave & 1) * 64;           // wave n-offset within tile

  f32x4 acc[MW][4];
#pragma unroll
  for (int i = 0; i < MW; ++i)
#pragma unroll
    for (int j = 0; j < 4; ++j) {
      acc[i][j][0] = 0.f; acc[i][j][1] = 0.f;
      acc[i][j][2] = 0.f; acc[i][j][3] = 0.f;
    }

  for (int k0 = 0; k0 < K; k0 += BK) {
    // ---- A staging: BM*4 cells of 8 floats; m fastest-in-row coalescing ----
#pragma unroll
    for (int c = 0; c < BM / 64; ++c) {
      int idx = tid + c * 256;          // 0 .. BM*4-1
      int m   = idx >> 2;               // 0 .. BM-1
      int k8  = idx & 3;                // 8-elem k-chunk
      const float* src = A + (size_t)(bm + m) * K + k0 + k8 * 8;
      float4 f0 = *(const float4*)src;
      float4 f1 = *(const float4*)(src + 4);
      bf16x8 pk;
      pk[0] = f2bf(f0.x); pk[1] = f2bf(f0.y); pk[2] = f2bf(f0.z); pk[3] = f2bf(f0.w);
      pk[4] = f2bf(f1.x); pk[5] = f2bf(f1.y); pk[6] = f2bf(f1.z); pk[7] = f2bf(f1.w);
      *(bf16x8*)&Als[(m >> 4) * 512 + (((m & 15) | (k8 << 4)) * 8)] = pk;
    }
    // ---- B staging with transpose: gather 8 k-values per column n ----
#pragma unroll
    for (int c = 0; c < 2; ++c) {
      int idx = tid + c * 256;          // 0..511
      int n   = idx & 127;
      int k8  = idx >> 7;
      const float* src = W + (size_t)(k0 + k8 * 8) * N + bn + n;
      bf16x8 pk;
#pragma unroll
      for (int j = 0; j < 8; ++j) pk[j] = f2bf(src[(size_t)j * N]);
      *(bf16x8*)&Bls[(n >> 4) * 512 + (((n & 15) | (k8 << 4)) * 8)] = pk;
    }
    __syncthreads();

    bf16x8 af[MW], bfr[4];
#pragma unroll
    for (int i = 0; i < MW; ++i)
      af[i] = *(bf16x8*)&Als[(wm / 16 + i) * 512 + lane * 8];
#pragma unroll
    for (int j = 0; j < 4; ++j)
      bfr[j] = *(bf16x8*)&Bls[(wn / 16 + j) * 512 + lane * 8];
#pragma unroll
    for (int i = 0; i < MW; ++i)
#pragma unroll
      for (int j = 0; j < 4; ++j)
        acc[i][j] = __builtin_amdgcn_mfma_f32_16x16x32_bf16(
            af[i], bfr[j], acc[i][j], 0, 0, 0);
    __syncthreads();
  }

  // ---- epilogue: C/D layout col=lane&15, row=quad*4+reg ----
  int quad = lane >> 4, col = lane & 15;
#pragma unroll
  for (int i = 0; i < MW; ++i) {
    int m0 = bm + wm + i * 16 + quad * 4;
#pragma unroll
    for (int j = 0; j < 4; ++j) {
      int n0 = bn + wn + j * 16 + col;
      float bval = bias ? bias[n0] : 0.f;
#pragma unroll
      for (int r = 0; r < 4; ++r) {
        int m = m0 + r;
        float v = acc[i][j][r] + bval;
        if (do_gelu) {
          v = 0.5f * v *
              (1.f + tanhf(0.7978845608028654f * (v + 0.044715f * v * v * v)));
        }
        if (resid) v += resid[(size_t)m * N + n0];
        size_t row;
        if (head_remap)
          row = ((size_t)(m >> 10) * NQ_CB + z) * T_SEQ + (m & (T_SEQ - 1));
        else
          row = m;
        C[row * (size_t)N + n0] = v;
      }
    }
  }
}

// ---------------------------------------------------------------------------
// Banded self-attention, WIN=5: 11 keys per query. One wave per (b,h,t).
// ---------------------------------------------------------------------------
__global__ __launch_bounds__(256) void self_attn_kernel(
    const float* __restrict__ q, const float* __restrict__ k,
    const float* __restrict__ v, float* __restrict__ o)
{
  int w = blockIdx.x * 4 + (threadIdx.x >> 6);  // (b*NHEAD + h)*T + t
  int lane = threadIdx.x & 63;
  int t = w & (T_SEQ - 1);
  int bh = w >> 10;
  int h = bh & (NHEAD - 1);
  int b = bh >> 4;
  size_t base = ((size_t)(b * T_SEQ) * DMODEL) + h * HDIM + lane;
  float qv = q[base + (size_t)t * DMODEL];

  float sc[2 * WIN + 1];
  float mx = -1e30f;
#pragma unroll
  for (int j = 0; j < 2 * WIN + 1; ++j) {
    int s = t - WIN + j;
    float d;
    if (s >= 0 && s < T_SEQ) {
      float kv = k[base + (size_t)s * DMODEL];
      d = qv * kv;
#pragma unroll
      for (int off = 32; off; off >>= 1) d += __shfl_xor(d, off, 64);
      d *= 0.125f;  // 1/sqrt(64)
    } else {
      d = -1e30f;
    }
    sc[j] = d;
    mx = fmaxf(mx, d);
  }
  float sum = 0.f;
#pragma unroll
  for (int j = 0; j < 2 * WIN + 1; ++j) {
    sc[j] = expf(sc[j] - mx);
    sum += sc[j];
  }
  float inv = 1.f / sum;
  float ov = 0.f;
#pragma unroll
  for (int j = 0; j < 2 * WIN + 1; ++j) {
    int s = t - WIN + j;
    if (s >= 0 && s < T_SEQ) ov += sc[j] * v[base + (size_t)s * DMODEL];
  }
  o[base + (size_t)t * DMODEL] = ov * inv;
}

// ---------------------------------------------------------------------------
// Cross-attention over NCOND=64 keys. One wave per (b,h,t).
// ---------------------------------------------------------------------------
__global__ __launch_bounds__(256) void cross_attn_kernel(
    const float* __restrict__ q, const float* __restrict__ k,
    const float* __restrict__ v, float* __restrict__ o)
{
  int w = blockIdx.x * 4 + (threadIdx.x >> 6);  // (b*NHEAD + h)*T + t
  int lane = threadIdx.x & 63;
  int t = w & (T_SEQ - 1);
  int h = (w >> 10) & (NHEAD - 1);
  int b = w >> 14;
  size_t qoff = ((size_t)(b * T_SEQ + t) * DMODEL) + h * HDIM;
  float qv = q[qoff + lane];

  const float* krow = k + ((size_t)(b * NCOND + lane) * DMODEL) + h * HDIM;
  float s_l = 0.f;
#pragma unroll
  for (int d = 0; d < HDIM; ++d) {
    float qd = __shfl(qv, d, 64);
    s_l += qd * krow[d];
  }
  s_l *= 0.125f;
  float m = s_l;
#pragma unroll
  for (int off = 32; off; off >>= 1) m = fmaxf(m, __shfl_xor(m, off, 64));
  float p = expf(s_l - m);
  float sum = p;
#pragma unroll
  for (int off = 32; off; off >>= 1) sum += __shfl_xor(sum, off, 64);
  p /= sum;

  float ov = 0.f;
  const float* vb = v + ((size_t)(b * NCOND) * DMODEL) + h * HDIM + lane;
#pragma unroll
  for (int s = 0; s < NCOND; ++s) {
    float ps = __shfl(p, s, 64);
    ov += ps * vb[(size_t)s * DMODEL];
  }
  o[qoff + lane] = ov;
}

// ---------------------------------------------------------------------------
// Host-side launch helpers
// ---------------------------------------------------------------------------
static inline void gemm_mfma(hipStream_t st, bool big,
    const float* A, const float* W0, const float* W1, const float* W2,
    size_t wstride, const float* b0, const float* b1, const float* b2,
    size_t bstride, const float* resid,
    float* C0, float* C1, float* C2,
    int M, int N, int K, int zdim, int do_gelu, int head_remap)
{
  dim3 grid(N / 128, M / (big ? 128 : 64), zdim);
  if (big)
    hipLaunchKernelGGL(gemm_bf16_kernel<4>, grid, dim3(256), 0, st,
                       A, W0, W1, W2, wstride, b0, b1, b2, bstride, resid,
                       C0, C1, C2, M, N, K, do_gelu, head_remap);
  else
    hipLaunchKernelGGL(gemm_bf16_kernel<2>, grid, dim3(256), 0, st,
                       A, W0, W1, W2, wstride, b0, b1, b2, bstride, resid,
                       C0, C1, C2, M, N, K, do_gelu, head_remap);
}

static inline void layernorm(hipStream_t st, const float* x, const float* g,
                             const float* b, float* y, int rows)
{
  hipLaunchKernelGGL(ln_kernel, dim3(rows), dim3(256), 0, st, x, g, b, y);
}

extern "C" void kernel_launch(void* const* d_in, const int* in_sizes, int n_in,
                              void* d_out, int out_size, void* d_ws, size_t ws_size,
                              hipStream_t stream)
{
  const int*   x     = (const int*)  d_in[0];
  const float* cond  = (const float*)d_in[1];
  const float* emb   = (const float*)d_in[2];
  const float* ln1_g = (const float*)d_in[3];
  const float* ln1_b = (const float*)d_in[4];
  const float* ln2_g = (const float*)d_in[5];
  const float* ln2_b = (const float*)d_in[6];
  const float* ln3_g = (const float*)d_in[7];
  const float* ln3_b = (const float*)d_in[8];
  const float* sWq   = (const float*)d_in[9];
  const float* sWk   = (const float*)d_in[10];
  const float* sWv   = (const float*)d_in[11];
  const float* sWo   = (const float*)d_in[12];
  const float* sbq   = (const float*)d_in[13];
  const float* sbk   = (const float*)d_in[14];
  const float* sbv   = (const float*)d_in[15];
  const float* sbo   = (const float*)d_in[16];
  const float* cWq   = (const float*)d_in[17];
  const float* cWk   = (const float*)d_in[18];
  const float* cWv   = (const float*)d_in[19];
  const float* cWo   = (const float*)d_in[20];
  const float* cbq   = (const float*)d_in[21];
  const float* cbk   = (const float*)d_in[22];
  const float* cbv   = (const float*)d_in[23];
  const float* cbo   = (const float*)d_in[24];
  const float* W1    = (const float*)d_in[25];
  const float* b1    = (const float*)d_in[26];
  const float* W2    = (const float*)d_in[27];
  const float* b2    = (const float*)d_in[28];
  const float* out_g = (const float*)d_in[29];
  const float* out_b = (const float*)d_in[30];
  const float* headW = (const float*)d_in[31];
  const float* headb = (const float*)d_in[32];

  float* out = (float*)d_out;
  float* ws  = (float*)d_ws;

  const int M = BATCH * T_SEQ;             // 2048
  const size_t SZ = (size_t)M * DMODEL;    // 2M floats (8 MB)
  float* h   = ws;
  float* tmp = ws + SZ;
  float* qb  = ws + 2 * SZ;
  float* kb  = ws + 3 * SZ;
  float* vb  = ws + 4 * SZ;
  float* ao  = ws + 5 * SZ;
  float* ffn = qb;  // (M, DFF) = 4*SZ floats, aliases qb..ao (free during FFN)

  hipLaunchKernelGGL(embed_kernel, dim3(M), dim3(256), 0, stream, x, emb, h);

  const int attn_blocks = BATCH * NHEAD * T_SEQ / 4;  // 4 waves per block

  for (int l = 0; l < NLAYER; ++l) {
    const size_t wDD = (size_t)l * DMODEL * DMODEL;
    const size_t wCD = (size_t)l * CONDD * DMODEL;
    const size_t wF1 = (size_t)l * DMODEL * DFF_SZ;
    const size_t wF2 = (size_t)l * DFF_SZ * DMODEL;
    const float* L1g = ln1_g + l * DMODEL, *L1b = ln1_b + l * DMODEL;
    const float* L2g = ln2_g + l * DMODEL, *L2b = ln2_b + l * DMODEL;
    const float* L3g = ln3_g + l * DMODEL, *L3b = ln3_b + l * DMODEL;

    // --- self attention block ---
    layernorm(stream, h, L1g, L1b, tmp, M);
    gemm_mfma(stream, true, tmp, sWq + wDD, sWk + wDD, sWv + wDD, 0,
              sbq + l * DMODEL, sbk + l * DMODEL, sbv + l * DMODEL, 0,
              nullptr, qb, kb, vb, M, DMODEL, DMODEL, 3, 0, 0);
    hipLaunchKernelGGL(self_attn_kernel, dim3(attn_blocks), dim3(256), 0, stream,
                       qb, kb, vb, ao);
    gemm_mfma(stream, false, ao, sWo + wDD, nullptr, nullptr, 0,
              sbo + l * DMODEL, nullptr, nullptr, 0,
              h, h, nullptr, nullptr, M, DMODEL, DMODEL, 1, 0, 0);

    // --- cross attention block ---
    layernorm(stream, h, L2g, L2b, tmp, M);
    gemm_mfma(stream, false, tmp, cWq + wDD, nullptr, nullptr, 0,
              cbq + l * DMODEL, nullptr, nullptr, 0,
              nullptr, qb, nullptr, nullptr, M, DMODEL, DMODEL, 1, 0, 0);
    gemm_mfma(stream, true, cond, cWk + wCD, cWv + wCD, nullptr, 0,
              cbk + l * DMODEL, cbv + l * DMODEL, nullptr, 0,
              nullptr, kb, vb, nullptr, BATCH * NCOND, DMODEL, CONDD, 2, 0, 0);
    hipLaunchKernelGGL(cross_attn_kernel, dim3(attn_blocks), dim3(256), 0, stream,
                       qb, kb, vb, ao);
    gemm_mfma(stream, false, ao, cWo + wDD, nullptr, nullptr, 0,
              cbo + l * DMODEL, nullptr, nullptr, 0,
              h, h, nullptr, nullptr, M, DMODEL, DMODEL, 1, 0, 0);

    // --- FFN block ---
    layernorm(stream, h, L3g, L3b, tmp, M);
    gemm_mfma(stream, true, tmp, W1 + wF1, nullptr, nullptr, 0,
              b1 + l * DFF_SZ, nullptr, nullptr, 0,
              nullptr, ffn, nullptr, nullptr, M, DFF_SZ, DMODEL, 1, 1, 0);
    gemm_mfma(stream, false, ffn, W2 + wF2, nullptr, nullptr, 0,
              b2 + l * DMODEL, nullptr, nullptr, 0,
              h, h, nullptr, nullptr, M, DMODEL, DFF_SZ, 1, 0, 0);
  }

  // --- output norm + per-codebook heads (batched over grid.z=4) ---
  layernorm(stream, h, out_g, out_b, tmp, M);
  gemm_mfma(stream, true, tmp, headW, nullptr, nullptr,
            (size_t)DMODEL * CARD_SZ, headb, nullptr, nullptr, CARD_SZ,
            nullptr, out, nullptr, nullptr, M, CARD_SZ, DMODEL, 4, 0, 1);
}

// Round 3
// 3900.648 us; speedup vs baseline: 3.5837x; 1.2638x over previous
//
#include <hip/hip_runtime.h>
#include <math.h>

// Problem constants (fixed by the reference)
#define BATCH   2
#define NQ_CB   4
#define T_SEQ   1024
#define DMODEL  1024
#define NHEAD   16
#define HDIM    64
#define NLAYER  8
#define CARD_SZ 1024
#define NCOND   64
#define CONDD   768
#define DFF_SZ  4096
#define WIN     5

typedef __attribute__((ext_vector_type(8))) short bf16x8;
typedef __attribute__((ext_vector_type(4))) float f32x4;
typedef unsigned short ushortx;

// float -> bf16 (RNE) raw bits
__device__ inline short f2bf(float f) {
  union { float f; unsigned u; } c;
  c.f = f;
  unsigned r = (c.u + 0x7FFFu + ((c.u >> 16) & 1u)) >> 16;
  return (short)r;
}
// bf16 raw bits -> float
__device__ inline float bf2f(unsigned short u) {
  union { unsigned u; float f; } c;
  c.u = ((unsigned)u) << 16;
  return c.f;
}

// async global->LDS, 16B per lane; lds dest = wave-uniform base + lane*16
__device__ inline void gld_lds16(const void* g, void* s) {
  __builtin_amdgcn_global_load_lds(
      (const __attribute__((address_space(1))) void*)g,
      (__attribute__((address_space(3))) void*)s, 16, 0, 0);
}

// ---------------------------------------------------------------------------
// Weight pack: fp32 (K,N) row-major -> bf16 fragment-layout slabs.
// slab (ng, kt) = 512 shorts; element (k,n):
//   dst[(ng*KT + kt)*512 + ((n&15)|(((k>>3)&3)<<4))*8 + (k&7)] ; ng=n>>4, kt=k>>5
// grid.z = matrix index in a (z,K,N) stack.
// ---------------------------------------------------------------------------
__global__ __launch_bounds__(256) void pack_kernel(
    const float* __restrict__ src, short* __restrict__ dst, int K, int N)
{
  size_t matoff = (size_t)blockIdx.z * K * N;
  src += matoff; dst += matoff;
  int gid = blockIdx.x * 256 + threadIdx.x;   // one bf16x8 cell per thread
  int slab = gid >> 6, cell = gid & 63;
  int KT = K >> 5;
  int ng = slab / KT, kt = slab - ng * KT;
  int n = ng * 16 + (cell & 15);
  int k = kt * 32 + (cell >> 4) * 8;
  bf16x8 pk;
#pragma unroll
  for (int j = 0; j < 8; ++j) pk[j] = f2bf(src[(size_t)(k + j) * N + n]);
  *(bf16x8*)&dst[(size_t)gid * 8] = pk;
}

// ---------------------------------------------------------------------------
// Embedding sum + sinusoidal positional embedding -> h (fp32)
// ---------------------------------------------------------------------------
__global__ __launch_bounds__(256) void embed_kernel(
    const int* __restrict__ x, const float* __restrict__ emb,
    float* __restrict__ h)
{
  int bt = blockIdx.x;
  int b = bt >> 10, t = bt & (T_SEQ - 1);
  int tid = threadIdx.x;
  float4 acc = make_float4(0.f, 0.f, 0.f, 0.f);
#pragma unroll
  for (int q = 0; q < NQ_CB; ++q) {
    int idx = x[(b * NQ_CB + q) * T_SEQ + t];
    const float4* er =
        (const float4*)(emb + ((size_t)q * (CARD_SZ + 1) + idx) * DMODEL);
    float4 e = er[tid];
    acc.x += e.x; acc.y += e.y; acc.z += e.z; acc.w += e.w;
  }
  int d0 = tid * 4;
  float c = -logf(10000.f) * (2.f / (float)DMODEL);
  float th0 = (float)t * expf(c * (float)(d0 >> 1));
  float th1 = (float)t * expf(c * (float)((d0 + 2) >> 1));
  acc.x += sinf(th0); acc.y += cosf(th0);
  acc.z += sinf(th1); acc.w += cosf(th1);
  ((float4*)(h + (size_t)bt * DMODEL))[tid] = acc;
}

// ---------------------------------------------------------------------------
// LayerNorm (fp32 in, bf16 out). One block per row.
// ---------------------------------------------------------------------------
__global__ __launch_bounds__(256) void ln_kernel(
    const float* __restrict__ x, const float* __restrict__ g,
    const float* __restrict__ b, ushortx* __restrict__ y)
{
  int row = blockIdx.x;
  int tid = threadIdx.x;
  const float4* xr = (const float4*)(x + (size_t)row * DMODEL);
  float4 v = xr[tid];
  float s  = v.x + v.y + v.z + v.w;
  float ss = v.x * v.x + v.y * v.y + v.z * v.z + v.w * v.w;
#pragma unroll
  for (int off = 32; off; off >>= 1) {
    s  += __shfl_xor(s, off, 64);
    ss += __shfl_xor(ss, off, 64);
  }
  __shared__ float sh_s[4], sh_ss[4];
  int w = tid >> 6;
  if ((tid & 63) == 0) { sh_s[w] = s; sh_ss[w] = ss; }
  __syncthreads();
  s  = sh_s[0] + sh_s[1] + sh_s[2] + sh_s[3];
  ss = sh_ss[0] + sh_ss[1] + sh_ss[2] + sh_ss[3];
  float mean = s * (1.f / DMODEL);
  float var  = ss * (1.f / DMODEL) - mean * mean;
  float rstd = rsqrtf(var + 1e-5f);
  float4 gv = ((const float4*)g)[tid];
  float4 bv = ((const float4*)b)[tid];
  ushort4 o;
  o.x = (ushortx)f2bf((v.x - mean) * rstd * gv.x + bv.x);
  o.y = (ushortx)f2bf((v.y - mean) * rstd * gv.y + bv.y);
  o.z = (ushortx)f2bf((v.z - mean) * rstd * gv.z + bv.z);
  o.w = (ushortx)f2bf((v.w - mean) * rstd * gv.w + bv.w);
  *(ushort4*)(y + (size_t)row * DMODEL + tid * 4) = o;
}

// ---------------------------------------------------------------------------
// bf16 MFMA GEMM, packed-B via global_load_lds.
// A: bf16 row-major (ABF16=1, DMA-staged) or fp32 row-major (ABF16=0, MW==2).
// Wp*: packed bf16 weights (layout above). Tile BMx128, BK=32, 4 waves 2x2.
// z decode: w = z%nw selects {W,b,C}; li = z/nw steps strides / head remap.
// flags: 1=gelu, 2=head_remap(li = codebook), 4=out bf16.
// ---------------------------------------------------------------------------
#define FL_GELU  1
#define FL_REMAP 2
#define FL_OBF16 4

template <int MW, int ABF16>
__global__ __launch_bounds__(256, 2) void gemm_pk(
    const void* __restrict__ Ain,
    const short* __restrict__ Wp0, const short* __restrict__ Wp1,
    const short* __restrict__ Wp2, long wstride, int nw,
    const float* __restrict__ b0, const float* __restrict__ b1,
    const float* __restrict__ b2, long bstride,
    const float* __restrict__ resid,
    void* __restrict__ C0v, void* __restrict__ C1v, void* __restrict__ C2v,
    long cstride,
    int M, int N, int K, int flags)
{
  const int BM = MW * 32;
  __shared__ __align__(16) short Als[BM * 32];   // BM/16 slabs of 512
  __shared__ __align__(16) short Bls[128 * 32];  // 8 slabs of 512

  int tid = threadIdx.x;
  int z = blockIdx.z;
  int w = z % nw, li = z / nw;
  const short* Wp = (w == 0 ? Wp0 : (w == 1 ? Wp1 : Wp2)) + (size_t)li * wstride;
  const float* bias = (w == 0 ? b0 : (w == 1 ? b1 : b2)) + (size_t)li * bstride;
  char* Cb = (char*)(w == 0 ? C0v : (w == 1 ? C1v : C2v)) + (size_t)li * cstride;

  int bm = blockIdx.y * BM;
  int bn = blockIdx.x * 128;
  int wave = tid >> 6, lane = tid & 63;
  int wm = (wave >> 1) * (MW * 16);
  int wn = (wave & 1) * 64;
  int KT = K >> 5;

  f32x4 acc[MW][4];
#pragma unroll
  for (int i = 0; i < MW; ++i)
#pragma unroll
    for (int j = 0; j < 4; ++j) {
      acc[i][j][0] = 0.f; acc[i][j][1] = 0.f;
      acc[i][j][2] = 0.f; acc[i][j][3] = 0.f;
    }

  for (int kt = 0; kt < KT; ++kt) {
    int k0 = kt * 32;
    // ---- B: 8 slabs of 1KB via DMA (2 per wave) ----
#pragma unroll
    for (int i = 0; i < 2; ++i) {
      int g = wave * 2 + i;
      const short* src = Wp + ((size_t)((bn >> 4) + g) * KT + kt) * 512 + lane * 8;
      gld_lds16(src, &Bls[g * 512]);
    }
    // ---- A ----
    if (ABF16) {
      const ushortx* A16 = (const ushortx*)Ain;
#pragma unroll
      for (int i = 0; i < (MW * 2 + 3) / 4; ++i) {
        int g = wave + i * 4;
        if (g < MW * 2) {
          const ushortx* src =
              A16 + (size_t)(bm + g * 16 + (lane & 15)) * K + k0 + (lane >> 4) * 8;
          gld_lds16(src, &Als[g * 512]);
        }
      }
    } else {  // fp32 A register staging (MW==2 only; used for cond)
      const float* Af = (const float*)Ain;
      int m = tid >> 2, k8 = tid & 3;
      const float* src = Af + (size_t)(bm + m) * K + k0 + k8 * 8;
      float4 f0 = *(const float4*)src;
      float4 f1 = *(const float4*)(src + 4);
      bf16x8 pk;
      pk[0] = f2bf(f0.x); pk[1] = f2bf(f0.y); pk[2] = f2bf(f0.z); pk[3] = f2bf(f0.w);
      pk[4] = f2bf(f1.x); pk[5] = f2bf(f1.y); pk[6] = f2bf(f1.z); pk[7] = f2bf(f1.w);
      *(bf16x8*)&Als[(m >> 4) * 512 + (((m & 15) | (k8 << 4)) * 8)] = pk;
    }
    __syncthreads();   // drains vmcnt -> DMA data visible

    bf16x8 af[MW], bfr[4];
#pragma unroll
    for (int i = 0; i < MW; ++i)
      af[i] = *(bf16x8*)&Als[((wm >> 4) + i) * 512 + lane * 8];
#pragma unroll
    for (int j = 0; j < 4; ++j)
      bfr[j] = *(bf16x8*)&Bls[((wn >> 4) + j) * 512 + lane * 8];
#pragma unroll
    for (int i = 0; i < MW; ++i)
#pragma unroll
      for (int j = 0; j < 4; ++j)
        acc[i][j] = __builtin_amdgcn_mfma_f32_16x16x32_bf16(
            af[i], bfr[j], acc[i][j], 0, 0, 0);
    __syncthreads();
  }

  // ---- epilogue (C/D layout: col=lane&15, row=quad*4+reg) ----
  int quad = lane >> 4, col = lane & 15;
#pragma unroll
  for (int i = 0; i < MW; ++i) {
    int m0 = bm + wm + i * 16 + quad * 4;
#pragma unroll
    for (int j = 0; j < 4; ++j) {
      int n0 = bn + wn + j * 16 + col;
      float bval = bias[n0];
#pragma unroll
      for (int r = 0; r < 4; ++r) {
        int m = m0 + r;
        float v = acc[i][j][r] + bval;
        if (flags & FL_GELU) {
          v = 0.5f * v *
              (1.f + tanhf(0.7978845608028654f * (v + 0.044715f * v * v * v)));
        }
        if (resid) v += resid[(size_t)m * N + n0];
        size_t row;
        if (flags & FL_REMAP)
          row = ((size_t)(m >> 10) * NQ_CB + li) * T_SEQ + (m & (T_SEQ - 1));
        else
          row = m;
        if (flags & FL_OBF16)
          ((ushortx*)Cb)[row * N + n0] = (ushortx)f2bf(v);
        else
          ((float*)Cb)[row * N + n0] = v;
      }
    }
  }
}

// ---------------------------------------------------------------------------
// Banded self-attention (WIN=5, 11 keys). One wave per (b,h,t). bf16 I/O.
// ---------------------------------------------------------------------------
__global__ __launch_bounds__(256) void self_attn_kernel(
    const ushortx* __restrict__ q, const ushortx* __restrict__ k,
    const ushortx* __restrict__ v, ushortx* __restrict__ o)
{
  int w = blockIdx.x * 4 + (threadIdx.x >> 6);
  int lane = threadIdx.x & 63;
  int t = w & (T_SEQ - 1);
  int bh = w >> 10;
  int h = bh & (NHEAD - 1);
  int b = bh >> 4;
  size_t base = ((size_t)(b * T_SEQ) * DMODEL) + h * HDIM + lane;
  float qv = bf2f(q[base + (size_t)t * DMODEL]);

  float sc[2 * WIN + 1];
  float mx = -1e30f;
#pragma unroll
  for (int j = 0; j < 2 * WIN + 1; ++j) {
    int s = t - WIN + j;
    float d;
    if (s >= 0 && s < T_SEQ) {
      float kv = bf2f(k[base + (size_t)s * DMODEL]);
      d = qv * kv;
#pragma unroll
      for (int off = 32; off; off >>= 1) d += __shfl_xor(d, off, 64);
      d *= 0.125f;
    } else {
      d = -1e30f;
    }
    sc[j] = d;
    mx = fmaxf(mx, d);
  }
  float sum = 0.f;
#pragma unroll
  for (int j = 0; j < 2 * WIN + 1; ++j) {
    sc[j] = expf(sc[j] - mx);
    sum += sc[j];
  }
  float inv = 1.f / sum;
  float ov = 0.f;
#pragma unroll
  for (int j = 0; j < 2 * WIN + 1; ++j) {
    int s = t - WIN + j;
    if (s >= 0 && s < T_SEQ) ov += sc[j] * bf2f(v[base + (size_t)s * DMODEL]);
  }
  o[base + (size_t)t * DMODEL] = (ushortx)f2bf(ov * inv);
}

// ---------------------------------------------------------------------------
// Cross-attention over NCOND=64 keys. One wave per (b,h,t). bf16 I/O.
// ---------------------------------------------------------------------------
__global__ __launch_bounds__(256) void cross_attn_kernel(
    const ushortx* __restrict__ q, const ushortx* __restrict__ k,
    const ushortx* __restrict__ v, ushortx* __restrict__ o)
{
  int w = blockIdx.x * 4 + (threadIdx.x >> 6);
  int lane = threadIdx.x & 63;
  int t = w & (T_SEQ - 1);
  int h = (w >> 10) & (NHEAD - 1);
  int b = w >> 14;
  size_t qoff = ((size_t)(b * T_SEQ + t) * DMODEL) + h * HDIM;
  float qv = bf2f(q[qoff + lane]);

  const ushortx* krow = k + ((size_t)(b * NCOND + lane) * DMODEL) + h * HDIM;
  float s_l = 0.f;
#pragma unroll
  for (int d = 0; d < HDIM; ++d) {
    float qd = __shfl(qv, d, 64);
    s_l += qd * bf2f(krow[d]);
  }
  s_l *= 0.125f;
  float m = s_l;
#pragma unroll
  for (int off = 32; off; off >>= 1) m = fmaxf(m, __shfl_xor(m, off, 64));
  float p = expf(s_l - m);
  float sum = p;
#pragma unroll
  for (int off = 32; off; off >>= 1) sum += __shfl_xor(sum, off, 64);
  p /= sum;

  float ov = 0.f;
  const ushortx* vb = v + ((size_t)(b * NCOND) * DMODEL) + h * HDIM + lane;
#pragma unroll
  for (int s = 0; s < NCOND; ++s) {
    float ps = __shfl(p, s, 64);
    ov += ps * bf2f(vb[(size_t)s * DMODEL]);
  }
  o[qoff + lane] = (ushortx)f2bf(ov);
}

// ---------------------------------------------------------------------------
// Host side
// ---------------------------------------------------------------------------
static void gemm_launch(hipStream_t st, int MW, int abf16,
    const void* A, const short* W0, const short* W1, const short* W2,
    long wstride, int nw,
    const float* b0, const float* b1, const float* b2, long bstride,
    const float* resid, void* C0, void* C1, void* C2, long cstride,
    int M, int N, int K, int z, int flags)
{
  dim3 grid(N / 128, M / (MW * 32), z);
  if (MW == 4)
    hipLaunchKernelGGL((gemm_pk<4, 1>), grid, dim3(256), 0, st, A, W0, W1, W2,
                       wstride, nw, b0, b1, b2, bstride, resid, C0, C1, C2,
                       cstride, M, N, K, flags);
  else if (abf16)
    hipLaunchKernelGGL((gemm_pk<2, 1>), grid, dim3(256), 0, st, A, W0, W1, W2,
                       wstride, nw, b0, b1, b2, bstride, resid, C0, C1, C2,
                       cstride, M, N, K, flags);
  else
    hipLaunchKernelGGL((gemm_pk<2, 0>), grid, dim3(256), 0, st, A, W0, W1, W2,
                       wstride, nw, b0, b1, b2, bstride, resid, C0, C1, C2,
                       cstride, M, N, K, flags);
}

extern "C" void kernel_launch(void* const* d_in, const int* in_sizes, int n_in,
                              void* d_out, int out_size, void* d_ws, size_t ws_size,
                              hipStream_t stream)
{
  const int*   x     = (const int*)  d_in[0];
  const float* cond  = (const float*)d_in[1];
  const float* emb   = (const float*)d_in[2];
  const float* ln1_g = (const float*)d_in[3];
  const float* ln1_b = (const float*)d_in[4];
  const float* ln2_g = (const float*)d_in[5];
  const float* ln2_b = (const float*)d_in[6];
  const float* ln3_g = (const float*)d_in[7];
  const float* ln3_b = (const float*)d_in[8];
  const float* sWq   = (const float*)d_in[9];
  const float* sWk   = (const float*)d_in[10];
  const float* sWv   = (const float*)d_in[11];
  const float* sWo   = (const float*)d_in[12];
  const float* sbq   = (const float*)d_in[13];
  const float* sbk   = (const float*)d_in[14];
  const float* sbv   = (const float*)d_in[15];
  const float* sbo   = (const float*)d_in[16];
  const float* cWq   = (const float*)d_in[17];
  const float* cWk   = (const float*)d_in[18];
  const float* cWv   = (const float*)d_in[19];
  const float* cWo   = (const float*)d_in[20];
  const float* cbq   = (const float*)d_in[21];
  const float* cbk   = (const float*)d_in[22];
  const float* cbv   = (const float*)d_in[23];
  const float* cbo   = (const float*)d_in[24];
  const float* W1    = (const float*)d_in[25];
  const float* b1    = (const float*)d_in[26];
  const float* W2    = (const float*)d_in[27];
  const float* b2    = (const float*)d_in[28];
  const float* out_g = (const float*)d_in[29];
  const float* out_b = (const float*)d_in[30];
  const float* headW = (const float*)d_in[31];
  const float* headb = (const float*)d_in[32];

  float* out = (float*)d_out;
  const size_t MB = 1u << 20;
  const long MAT = 1048576L;           // 1024*1024
  const long CMAT = 768L * 1024;       // cWk/cWv per-layer elements
  const long FMAT = 4L * 1048576;      // W1/W2 per-layer elements
  const int M = BATCH * T_SEQ;         // 2048

  char* wsb = (char*)d_ws;
  float*   h   = (float*)(wsb);              // 8 MB fp32
  ushortx* tmp = (ushortx*)(wsb + 8 * MB);   // 4 MB bf16
  ushortx* qb  = (ushortx*)(wsb + 12 * MB);
  ushortx* kb  = (ushortx*)(wsb + 16 * MB);
  ushortx* vb  = (ushortx*)(wsb + 20 * MB);
  ushortx* ao  = (ushortx*)(wsb + 24 * MB);
  ushortx* ffn = qb;                          // 16 MB bf16, aliases qb..ao
  ushortx* ckv = (ushortx*)(wsb + 28 * MB);   // 4 MB bf16 (16 slabs 128x1024)
  short*   PB  = (short*)(wsb + 32 * MB);     // pack region

  bool big = ws_size >= (size_t)32 * MB + (size_t)268435456;

  auto pack = [&](const float* src, short* dst, int K, int N, int z) {
    hipLaunchKernelGGL(pack_kernel, dim3((unsigned)((size_t)K * N / 2048), 1, z),
                       dim3(256), 0, stream, src, dst, K, N);
  };

  // Upfront pack (big path): fixed offsets in shorts
  short *Pq = PB, *Pk = PB + 8 * MAT, *Pv = PB + 16 * MAT, *Po = PB + 24 * MAT;
  short *Pcq = PB + 32 * MAT, *Pco = PB + 40 * MAT;
  short *Pck = PB + 48 * MAT, *Pcv = PB + 54 * MAT;
  short *Pw1 = PB + 60 * MAT, *Pw2 = PB + 92 * MAT, *Phd = PB + 124 * MAT;
  if (big) {
    pack(sWq, Pq, 1024, 1024, 8);  pack(sWk, Pk, 1024, 1024, 8);
    pack(sWv, Pv, 1024, 1024, 8);  pack(sWo, Po, 1024, 1024, 8);
    pack(cWq, Pcq, 1024, 1024, 8); pack(cWo, Pco, 1024, 1024, 8);
    pack(cWk, Pck, 768, 1024, 8);  pack(cWv, Pcv, 768, 1024, 8);
    pack(W1, Pw1, 1024, 4096, 8);  pack(W2, Pw2, 4096, 1024, 8);
    pack(headW, Phd, 1024, 1024, 4);
  }

  hipLaunchKernelGGL(embed_kernel, dim3(M), dim3(256), 0, stream, x, emb, h);

  // ---- cross K/V for all layers (cond is layer-invariant) ----
  if (big) {
    gemm_launch(stream, 2, 0, cond, Pck, Pcv, nullptr, CMAT, 2,
                cbk, cbv, nullptr, 1024, nullptr,
                ckv, (char*)ckv + 262144, nullptr, 524288,
                BATCH * NCOND, DMODEL, CONDD, 16, FL_OBF16);
  } else {
    pack(cWk, PB, 768, 1024, 8);
    gemm_launch(stream, 2, 0, cond, PB, nullptr, nullptr, CMAT, 1,
                cbk, nullptr, nullptr, 1024, nullptr,
                ckv, nullptr, nullptr, 524288,
                BATCH * NCOND, DMODEL, CONDD, 8, FL_OBF16);
    pack(cWv, PB, 768, 1024, 8);
    gemm_launch(stream, 2, 0, cond, PB, nullptr, nullptr, CMAT, 1,
                cbv, nullptr, nullptr, 1024, nullptr,
                (char*)ckv + 262144, nullptr, nullptr, 524288,
                BATCH * NCOND, DMODEL, CONDD, 8, FL_OBF16);
  }

  const int attn_blocks = BATCH * NHEAD * T_SEQ / 4;

  for (int l = 0; l < NLAYER; ++l) {
    const float* L1g = ln1_g + l * DMODEL, *L1b = ln1_b + l * DMODEL;
    const float* L2g = ln2_g + l * DMODEL, *L2b = ln2_b + l * DMODEL;
    const float* L3g = ln3_g + l * DMODEL, *L3b = ln3_b + l * DMODEL;

    // --- self attention ---
    hipLaunchKernelGGL(ln_kernel, dim3(M), dim3(256), 0, stream, h, L1g, L1b, tmp);
    {
      const short *wq, *wk, *wv;
      if (big) { wq = Pq + l * MAT; wk = Pk + l * MAT; wv = Pv + l * MAT; }
      else {
        pack(sWq + (size_t)l * MAT, PB, 1024, 1024, 1);
        pack(sWk + (size_t)l * MAT, PB + MAT, 1024, 1024, 1);
        pack(sWv + (size_t)l * MAT, PB + 2 * MAT, 1024, 1024, 1);
        wq = PB; wk = PB + MAT; wv = PB + 2 * MAT;
      }
      gemm_launch(stream, 4, 1, tmp, wq, wk, wv, 0, 3,
                  sbq + l * DMODEL, sbk + l * DMODEL, sbv + l * DMODEL, 0,
                  nullptr, qb, kb, vb, 0, M, DMODEL, DMODEL, 3, FL_OBF16);
    }
    hipLaunchKernelGGL(self_attn_kernel, dim3(attn_blocks), dim3(256), 0, stream,
                       qb, kb, vb, ao);
    {
      const short* wo = big ? Po + l * MAT : PB;
      if (!big) pack(sWo + (size_t)l * MAT, PB, 1024, 1024, 1);
      gemm_launch(stream, 2, 1, ao, wo, nullptr, nullptr, 0, 1,
                  sbo + l * DMODEL, nullptr, nullptr, 0,
                  h, h, nullptr, nullptr, 0, M, DMODEL, DMODEL, 1, 0);
    }

    // --- cross attention ---
    hipLaunchKernelGGL(ln_kernel, dim3(M), dim3(256), 0, stream, h, L2g, L2b, tmp);
    {
      const short* wcq = big ? Pcq + l * MAT : PB;
      if (!big) pack(cWq + (size_t)l * MAT, PB, 1024, 1024, 1);
      gemm_launch(stream, 2, 1, tmp, wcq, nullptr, nullptr, 0, 1,
                  cbq + l * DMODEL, nullptr, nullptr, 0,
                  nullptr, qb, nullptr, nullptr, 0, M, DMODEL, DMODEL, 1, FL_OBF16);
    }
    hipLaunchKernelGGL(cross_attn_kernel, dim3(attn_blocks), dim3(256), 0, stream,
                       qb, ckv + (size_t)(2 * l) * 131072,
                       ckv + (size_t)(2 * l + 1) * 131072, ao);
    {
      const short* wco = big ? Pco + l * MAT : PB;
      if (!big) pack(cWo + (size_t)l * MAT, PB, 1024, 1024, 1);
      gemm_launch(stream, 2, 1, ao, wco, nullptr, nullptr, 0, 1,
                  cbo + l * DMODEL, nullptr, nullptr, 0,
                  h, h, nullptr, nullptr, 0, M, DMODEL, DMODEL, 1, 0);
    }

    // --- FFN ---
    hipLaunchKernelGGL(ln_kernel, dim3(M), dim3(256), 0, stream, h, L3g, L3b, tmp);
    {
      const short* w1p = big ? Pw1 + l * FMAT : PB;
      if (!big) pack(W1 + (size_t)l * FMAT, PB, 1024, 4096, 1);
      gemm_launch(stream, 4, 1, tmp, w1p, nullptr, nullptr, 0, 1,
                  b1 + l * DFF_SZ, nullptr, nullptr, 0,
                  nullptr, ffn, nullptr, nullptr, 0,
                  M, DFF_SZ, DMODEL, 1, FL_GELU | FL_OBF16);
      const short* w2p = big ? Pw2 + l * FMAT : PB;
      if (!big) pack(W2 + (size_t)l * FMAT, PB, 4096, 1024, 1);
      gemm_launch(stream, 2, 1, ffn, w2p, nullptr, nullptr, 0, 1,
                  b2 + l * DMODEL, nullptr, nullptr, 0,
                  h, h, nullptr, nullptr, 0, M, DMODEL, DFF_SZ, 1, 0);
    }
  }

  // --- output norm + heads (batched z=4, row-remapped) ---
  hipLaunchKernelGGL(ln_kernel, dim3(M), dim3(256), 0, stream, h, out_g, out_b, tmp);
  {
    const short* whd = big ? Phd : PB;
    if (!big) pack(headW, PB, 1024, 1024, 4);
    gemm_launch(stream, 4, 1, tmp, whd, nullptr, nullptr, MAT, 1,
                headb, nullptr, nullptr, CARD_SZ, nullptr,
                out, nullptr, nullptr, 0, M, CARD_SZ, DMODEL, 4, FL_REMAP);
  }
}